// Round 6
// baseline (237.983 us; speedup 1.0000x reference)
//
#include <hip/hip_runtime.h>
#include <hip/hip_bf16.h>
#include <cstdint>

typedef __attribute__((ext_vector_type(8))) short bf16x8;
typedef __attribute__((ext_vector_type(4))) short bf16x4;
typedef __attribute__((ext_vector_type(4))) float f32x4;

#define TANH_SCALE 2.8853900817779268f   // 2*log2(e)
#define TANH_UNSCALE 0.34657359027997264f // ln2/2

__device__ __forceinline__ short cvt_bf16(float f) {
  union { float f; uint32_t u; } x; x.f = f;
  uint32_t r = x.u + 0x7FFFu + ((x.u >> 16) & 1u);  // RNE
  return (short)(r >> 16);
}
__device__ __forceinline__ float bf16_to_f(short s) {
  union { uint32_t u; float f; } x; x.u = ((uint32_t)(uint16_t)s) << 16;
  return x.f;
}

// tanh(x) = 1 - 2/(e^{2x}+1); exp2 form never overflows the denominator.
__device__ __forceinline__ float tanh_fast(float x) {
  float e = __builtin_amdgcn_exp2f(x * TANH_SCALE);
  return 1.0f - 2.0f * __builtin_amdgcn_rcpf(e + 1.0f);
}
// input already scaled by TANH_SCALE
__device__ __forceinline__ float tanh_pre(float xs) {
  float e = __builtin_amdgcn_exp2f(xs);
  return 1.0f - 2.0f * __builtin_amdgcn_rcpf(e + 1.0f);
}

// async global->LDS, 16 B per lane; lds base must be wave-uniform (lane i lands at base+16*i)
__device__ __forceinline__ void load_lds16(void* lds, const void* g) {
  __builtin_amdgcn_global_load_lds(
      (const __attribute__((address_space(1))) void*)g,
      (__attribute__((address_space(3))) void*)lds, 16, 0, 0);
}

// ---------- f32 -> (hi,lo) bf16 split convert ----------
__global__ __launch_bounds__(256) void k_convert_split(const float* __restrict__ in,
                                                       short* __restrict__ hi,
                                                       short* __restrict__ lo, int n4) {
  int i = blockIdx.x * 256 + threadIdx.x;
  int stride = gridDim.x * 256;
  for (; i < n4; i += stride) {
    float4 v = ((const float4*)in)[i];
    bf16x4 h, l;
    h.x = cvt_bf16(v.x); h.y = cvt_bf16(v.y); h.z = cvt_bf16(v.z); h.w = cvt_bf16(v.w);
    l.x = cvt_bf16(v.x - bf16_to_f(h.x));
    l.y = cvt_bf16(v.y - bf16_to_f(h.y));
    l.z = cvt_bf16(v.z - bf16_to_f(h.z));
    l.w = cvt_bf16(v.w - bf16_to_f(h.w));
    ((bf16x4*)hi)[i] = h;
    ((bf16x4*)lo)[i] = l;
  }
}

// ---------- LDS-tiled transpose + f32->bf16 split: out[c*R+r] = in[r*C+c] ----------
__global__ __launch_bounds__(256) void k_transpose_split(const float* __restrict__ in,
                                                         short* __restrict__ hi,
                                                         short* __restrict__ lo,
                                                         int R, int C) {
  __shared__ float tile[32][33];
  int r0 = blockIdx.x * 32, c0 = blockIdx.y * 32;
  int j = threadIdx.x & 31, i0 = threadIdx.x >> 5;
  #pragma unroll
  for (int i = i0; i < 32; i += 8) {
    int c = c0 + j;
    tile[i][j] = (c < C) ? in[(size_t)(r0 + i) * C + c] : 0.f;
  }
  __syncthreads();
  #pragma unroll
  for (int i = i0; i < 32; i += 8) {
    float v = tile[j][i];
    short h = cvt_bf16(v);
    hi[(size_t)(c0 + i) * R + r0 + j] = h;
    lo[(size_t)(c0 + i) * R + r0 + j] = cvt_bf16(v - bf16_to_f(h));
  }
}

// ---------- plain transpose + cvt (for w4, zero-pad cols >= C) ----------
__global__ __launch_bounds__(256) void k_transpose_cvt(const float* __restrict__ in,
                                                       short* __restrict__ out,
                                                       int R, int C) {
  __shared__ float tile[32][33];
  int r0 = blockIdx.x * 32, c0 = blockIdx.y * 32;
  int j = threadIdx.x & 31, i0 = threadIdx.x >> 5;
  #pragma unroll
  for (int i = i0; i < 32; i += 8) {
    int c = c0 + j;
    tile[i][j] = (c < C) ? in[(size_t)(r0 + i) * C + c] : 0.f;
  }
  __syncthreads();
  #pragma unroll
  for (int i = i0; i < 32; i += 8)
    out[(size_t)(c0 + i) * R + r0 + j] = cvt_bf16(tile[j][i]);
}

// ---------- fb[b][t][a] = text[b,t,:] . w2[:,a] + bias[a]  (K=300, exact f32) ----------
__global__ __launch_bounds__(256) void k_fb(const float* __restrict__ text,
                                            const float* __restrict__ w2,
                                            const float* __restrict__ bias,
                                            float* __restrict__ fb) {
  int b = blockIdx.x, t0 = blockIdx.y * 8, a = threadIdx.x;
  float acc[8] = {0.f,0.f,0.f,0.f,0.f,0.f,0.f,0.f};
  const float* tp = text + ((size_t)b * 40 + t0) * 300;
  for (int k = 0; k < 300; k++) {
    float wv = w2[k * 256 + a];
    #pragma unroll
    for (int j = 0; j < 8; j++) acc[j] += tp[j * 300 + k] * wv;
  }
  float bv = bias[a];
  #pragma unroll
  for (int j = 0; j < 8; j++)
    fb[((size_t)b * 40 + t0 + j) * 256 + a] = acc[j] + bv;
}

// ---------- split-bf16 e-GEMM, m97-style: 128x64 tile, BK=64, global_load_lds ----------
// C = Ah*Bh^T + Ah*Bl^T + Al*Bh^T  (~f32 precision). 512 thr = 8 waves; wave = 16-row m-tile.
__global__ __launch_bounds__(512) void k_gemm_e(const short* __restrict__ Ah,
                                                const short* __restrict__ Al,
                                                const short* __restrict__ BTh,
                                                const short* __restrict__ BTl,
                                                float* __restrict__ C,
                                                int K, int ldc) {
  __shared__ __align__(16) short Ash[128][64];  // 16 KB (async-copy layout, unpadded)
  __shared__ __align__(16) short Asl[128][64];  // 16 KB
  __shared__ __align__(16) short Bsh[64][64];   //  8 KB
  __shared__ __align__(16) short Bsl[64][64];   //  8 KB
  int m0 = blockIdx.x * 128, n0 = blockIdx.y * 64;
  int tid = threadIdx.x, lane = tid & 63, wave = tid >> 6;
  int wm = wave * 16;
  int mrow = lane & 15, quad = lane >> 4;
  int lrow = lane >> 3, lseg = (lane & 7) * 8;  // 8 rows x 8 segs per 1KB chunk

  f32x4 acc[4];
  #pragma unroll
  for (int j = 0; j < 4; j++) acc[j] = (f32x4){0.f, 0.f, 0.f, 0.f};

  for (int k0 = 0; k0 < K; k0 += 64) {
    __syncthreads();  // previous iteration's fragment reads done
    // A: 16 chunks of 8 rows per buffer; wave takes 2 each of Ah/Al
    #pragma unroll
    for (int i = 0; i < 2; i++) {
      int c = wave * 2 + i;
      load_lds16(&Ash[c * 8][0], Ah + (size_t)(m0 + c * 8 + lrow) * K + k0 + lseg);
      load_lds16(&Asl[c * 8][0], Al + (size_t)(m0 + c * 8 + lrow) * K + k0 + lseg);
    }
    // B: 8 chunks per buffer; wave takes 1 each of Bh/Bl
    load_lds16(&Bsh[wave * 8][0], BTh + (size_t)(n0 + wave * 8 + lrow) * K + k0 + lseg);
    load_lds16(&Bsl[wave * 8][0], BTl + (size_t)(n0 + wave * 8 + lrow) * K + k0 + lseg);
    __syncthreads();  // drains vmcnt -> LDS tiles ready
    #pragma unroll
    for (int ks = 0; ks < 2; ks++) {
      int kk = ks * 32 + quad * 8;
      bf16x8 ah = *(const bf16x8*)&Ash[wm + mrow][kk];
      bf16x8 al = *(const bf16x8*)&Asl[wm + mrow][kk];
      bf16x8 bh[4], bl[4];
      #pragma unroll
      for (int j = 0; j < 4; j++) {
        bh[j] = *(const bf16x8*)&Bsh[j * 16 + mrow][kk];
        bl[j] = *(const bf16x8*)&Bsl[j * 16 + mrow][kk];
      }
      #pragma unroll
      for (int j = 0; j < 4; j++) {
        acc[j] = __builtin_amdgcn_mfma_f32_16x16x32_bf16(ah, bh[j], acc[j], 0, 0, 0);
        acc[j] = __builtin_amdgcn_mfma_f32_16x16x32_bf16(ah, bl[j], acc[j], 0, 0, 0);
        acc[j] = __builtin_amdgcn_mfma_f32_16x16x32_bf16(al, bh[j], acc[j], 0, 0, 0);
      }
    }
  }
  int rbase = quad * 4;
  #pragma unroll
  for (int j = 0; j < 4; j++) {
    int col = n0 + j * 16 + mrow;
    #pragma unroll
    for (int r = 0; r < 4; r++) {
      int row = m0 + wm + rbase + r;
      C[(size_t)row * ldc + col] = acc[j][r];
    }
  }
}

// ---------- final GEMM, m97-style: 128x64 tile, BK=64, global_load_lds(16B) ----------
__global__ __launch_bounds__(256) void k_gemm_f(const short* __restrict__ A,
                                                const short* __restrict__ BT,
                                                const float* __restrict__ bias,
                                                float* __restrict__ C,
                                                int K, int ldc, int nstore) {
  __shared__ __align__(16) short As[128][64];  // 16 KB, unpadded (async-copy layout)
  __shared__ __align__(16) short Bs[64][64];   //  8 KB
  int m0 = blockIdx.x * 128, n0 = blockIdx.y * 64;
  int tid = threadIdx.x, lane = tid & 63, wave = tid >> 6;
  int wm = wave * 32;
  int mrow = lane & 15, quad = lane >> 4;
  int lrow = lane >> 3, lseg = (lane & 7) * 8;

  f32x4 acc[2][4];
  #pragma unroll
  for (int i = 0; i < 2; i++)
    #pragma unroll
    for (int j = 0; j < 4; j++) acc[i][j] = (f32x4){0.f, 0.f, 0.f, 0.f};

  for (int k0 = 0; k0 < K; k0 += 64) {
    __syncthreads();
    #pragma unroll
    for (int i = 0; i < 4; i++) {
      int c = wave * 4 + i;
      load_lds16(&As[c * 8][0], A + (size_t)(m0 + c * 8 + lrow) * K + k0 + lseg);
    }
    #pragma unroll
    for (int i = 0; i < 2; i++) {
      int c = wave * 2 + i;
      load_lds16(&Bs[c * 8][0], BT + (size_t)(n0 + c * 8 + lrow) * K + k0 + lseg);
    }
    __syncthreads();
    #pragma unroll
    for (int ks = 0; ks < 2; ks++) {
      int kk = ks * 32 + quad * 8;
      bf16x8 af[2], bf[4];
      #pragma unroll
      for (int i = 0; i < 2; i++) af[i] = *(const bf16x8*)&As[wm + i * 16 + mrow][kk];
      #pragma unroll
      for (int j = 0; j < 4; j++) bf[j] = *(const bf16x8*)&Bs[j * 16 + mrow][kk];
      #pragma unroll
      for (int i = 0; i < 2; i++)
        #pragma unroll
        for (int j = 0; j < 4; j++)
          acc[i][j] = __builtin_amdgcn_mfma_f32_16x16x32_bf16(af[i], bf[j], acc[i][j], 0, 0, 0);
    }
  }
  int rbase = quad * 4;
  #pragma unroll
  for (int i = 0; i < 2; i++)
    #pragma unroll
    for (int j = 0; j < 4; j++) {
      int col = n0 + j * 16 + mrow;
      if (col < nstore) {
        float bv = bias[col];
        #pragma unroll
        for (int r = 0; r < 4; r++) {
          int row = m0 + wm + i * 16 + rbase + r;
          C[(size_t)row * ldc + col] = acc[i][j][r] + bv;
        }
      }
    }
}

// ---------- fused middle v6: 2 rows/wave, chunked butterflies, pre-scaled tanh inputs ----------
// fbs stores (f+bias)*TANH_SCALE; e kept both raw and scaled. Saves one v_mul per tanh in phase 1.
__global__ __launch_bounds__(512) void k_middle(const float* __restrict__ e,
                                                const float* __restrict__ fb,
                                                const float* __restrict__ w3,
                                                const float* __restrict__ bias,
                                                short* __restrict__ cont) {
  __shared__ __align__(16) float fbs[40 * 256];  // 40 KB (scaled)
  __shared__ float lg[16][40];
  __shared__ float attn[16][40];
  int tid = threadIdx.x, wave = tid >> 6, lane = tid & 63;
  int row0 = blockIdx.x * 16;
  int b = row0 >> 9;          // 512 rows per batch; 16 | 512 so block is batch-pure
  int rowA = row0 + wave, rowB = rowA + 8;

  const float4* fsrc = (const float4*)(fb + (size_t)b * 40 * 256);
  for (int i = tid; i < 40 * 64; i += 512) {
    float4 v = fsrc[i];
    v.x *= TANH_SCALE; v.y *= TANH_SCALE; v.z *= TANH_SCALE; v.w *= TANH_SCALE;
    ((float4*)fbs)[i] = v;
  }
  __syncthreads();

  int a0 = lane * 4;
  float4 eA  = *(const float4*)(e + (size_t)rowA * 256 + a0);
  float4 eB  = *(const float4*)(e + (size_t)rowB * 256 + a0);
  float4 w34 = *(const float4*)(w3 + a0);
  float4 bv4 = *(const float4*)(bias + a0);
  float4 eAs, eBs;
  eAs.x = eA.x * TANH_SCALE; eAs.y = eA.y * TANH_SCALE;
  eAs.z = eA.z * TANH_SCALE; eAs.w = eA.w * TANH_SCALE;
  eBs.x = eB.x * TANH_SCALE; eBs.y = eB.y * TANH_SCALE;
  eBs.z = eB.z * TANH_SCALE; eBs.w = eB.w * TANH_SCALE;

  // phase 1: logits in chunks of 4 t, both rows; 8 independent butterfly chains
  for (int tc = 0; tc < 40; tc += 4) {
    float pa[4], pb[4];
    #pragma unroll
    for (int u = 0; u < 4; u++) {
      float4 f4 = *(const float4*)&fbs[(tc + u) * 256 + a0];
      pa[u] = tanh_pre(eAs.x + f4.x) * w34.x + tanh_pre(eAs.y + f4.y) * w34.y
            + tanh_pre(eAs.z + f4.z) * w34.z + tanh_pre(eAs.w + f4.w) * w34.w;
      pb[u] = tanh_pre(eBs.x + f4.x) * w34.x + tanh_pre(eBs.y + f4.y) * w34.y
            + tanh_pre(eBs.z + f4.z) * w34.z + tanh_pre(eBs.w + f4.w) * w34.w;
    }
    #pragma unroll
    for (int s = 32; s >= 1; s >>= 1) {
      #pragma unroll
      for (int u = 0; u < 4; u++) {
        pa[u] += __shfl_xor(pa[u], s, 64);
        pb[u] += __shfl_xor(pb[u], s, 64);
      }
    }
    if (lane == 0) {
      #pragma unroll
      for (int u = 0; u < 4; u++) { lg[wave][tc + u] = pa[u]; lg[wave + 8][tc + u] = pb[u]; }
    }
  }

  // phase 2: wave-local softmax per row (lanes >= 40 idle via -inf/0)
  auto softmax_row = [&](int r) {
    float x = (lane < 40) ? lg[r][lane] : -3.0e38f;
    float m = x;
    #pragma unroll
    for (int s = 32; s >= 1; s >>= 1) m = fmaxf(m, __shfl_xor(m, s, 64));
    float ex = (lane < 40) ? __builtin_amdgcn_exp2f((x - m) * 1.4426950408889634f) : 0.f;
    float ssum = ex;
    #pragma unroll
    for (int s = 32; s >= 1; s >>= 1) ssum += __shfl_xor(ssum, s, 64);
    if (lane < 40) attn[r][lane] = ex * __builtin_amdgcn_rcpf(ssum);
  };
  softmax_row(wave);
  softmax_row(wave + 8);

  // phase 3: text_attn = (sum_t attn[t]*fbs_scaled[t][chunk]) * (1/SCALE) - bias
  float ax = 0.f, ay = 0.f, az = 0.f, aw = 0.f;
  float bx = 0.f, by = 0.f, bz = 0.f, bw = 0.f;
  for (int t = 0; t < 40; t++) {
    float wa = attn[wave][t], wb = attn[wave + 8][t];  // wave-uniform broadcasts
    float4 f4 = *(const float4*)&fbs[t * 256 + a0];
    ax += wa * f4.x; ay += wa * f4.y; az += wa * f4.z; aw += wa * f4.w;
    bx += wb * f4.x; by += wb * f4.y; bz += wb * f4.z; bw += wb * f4.w;
  }
  ax = ax * TANH_UNSCALE - bv4.x; ay = ay * TANH_UNSCALE - bv4.y;
  az = az * TANH_UNSCALE - bv4.z; aw = aw * TANH_UNSCALE - bv4.w;
  bx = bx * TANH_UNSCALE - bv4.x; by = by * TANH_UNSCALE - bv4.y;
  bz = bz * TANH_UNSCALE - bv4.z; bw = bw * TANH_UNSCALE - bv4.w;

  auto emit = [&](int row, float4 e4, float tx, float ty, float tz, float tw) {
    short* crow = cont + (size_t)row * 1024 + a0;
    auto st4 = [&](int off, float x, float y, float z, float w) {
      uint32_t lo = (uint32_t)(uint16_t)cvt_bf16(x) | ((uint32_t)(uint16_t)cvt_bf16(y) << 16);
      uint32_t hi = (uint32_t)(uint16_t)cvt_bf16(z) | ((uint32_t)(uint16_t)cvt_bf16(w) << 16);
      uint2 pk; pk.x = lo; pk.y = hi;
      *(uint2*)(crow + off) = pk;
    };
    st4(0,   tanh_fast(e4.x), tanh_fast(e4.y), tanh_fast(e4.z), tanh_fast(e4.w));
    st4(256, tanh_fast(tx),   tanh_fast(ty),   tanh_fast(tz),   tanh_fast(tw));
    st4(512, tanh_fast(e4.x * tx), tanh_fast(e4.y * ty),
             tanh_fast(e4.z * tz), tanh_fast(e4.w * tw));
    st4(768, tanh_fast(e4.x - tx), tanh_fast(e4.y - ty),
             tanh_fast(e4.z - tz), tanh_fast(e4.w - tw));
  };
  emit(rowA, eA, ax, ay, az, aw);
  emit(rowB, eB, bx, by, bz, bw);
}

extern "C" void kernel_launch(void* const* d_in, const int* in_sizes, int n_in,
                              void* d_out, int out_size, void* d_ws, size_t ws_size,
                              hipStream_t stream) {
  const float* video = (const float*)d_in[0];  // 16x512x1024
  const float* text  = (const float*)d_in[1];  // 16x40x300
  const float* w1    = (const float*)d_in[2];  // 1024x256
  const float* w2    = (const float*)d_in[3];  // 300x256
  const float* w3    = (const float*)d_in[4];  // 256
  const float* bias  = (const float*)d_in[5];  // 256
  const float* w4    = (const float*)d_in[6];  // 1024x500
  const float* b4    = (const float*)d_in[7];  // 500
  float* out = (float*)d_out;                  // 16x512x500
  char* ws = (char*)d_ws;

  // workspace layout (bytes)
  short* video_hi = (short*)(ws);              // 8192x1024 bf16 = 16,777,216
  short* video_lo = (short*)(ws + 16777216);   // 8192x1024 bf16 = 16,777,216 (aliased w/ contbuf)
  short* contbuf  = (short*)(ws + 16777216);   // dead until after e-GEMM consumes video_lo
  short* w1T_hi   = (short*)(ws + 33554432);   // 256x1024 bf16 = 524,288
  short* w1T_lo   = (short*)(ws + 34078720);   // 256x1024 bf16 = 524,288
  short* w4T      = (short*)(ws + 34603008);   // 512x1024 bf16 = 1,048,576 (rows 500..511 zero)
  float* fbuf     = (float*)(ws + 35651584);   // 16x40x256 f32 = 655,360 (f + bias)
  float* ebuf     = (float*)(ws + 36306944);   // 8192x256 f32  = 8,388,608

  k_convert_split<<<2048, 256, 0, stream>>>(video, video_hi, video_lo, 8388608 / 4);
  k_transpose_split<<<dim3(32, 8), 256, 0, stream>>>(w1, w1T_hi, w1T_lo, 1024, 256);
  k_transpose_cvt<<<dim3(32, 16), 256, 0, stream>>>(w4, w4T, 1024, 500);
  k_fb<<<dim3(16, 5), 256, 0, stream>>>(text, w2, bias, fbuf);
  k_gemm_e<<<dim3(64, 4), 512, 0, stream>>>(video_hi, video_lo, w1T_hi, w1T_lo,
                                            ebuf, 1024, 256);
  k_middle<<<512, 512, 0, stream>>>(ebuf, fbuf, w3, bias, contbuf);
  k_gemm_f<<<dim3(64, 8), 256, 0, stream>>>(contbuf, w4T, b4, out, 1024, 500, 500);
}

// Round 7
// 196.145 us; speedup vs baseline: 1.2133x; 1.2133x over previous
//
#include <hip/hip_runtime.h>
#include <hip/hip_bf16.h>
#include <cstdint>

typedef __attribute__((ext_vector_type(8))) short bf16x8;
typedef __attribute__((ext_vector_type(4))) short bf16x4;
typedef __attribute__((ext_vector_type(4))) float f32x4;

#define TANH_SCALE 2.8853900817779268f    // 2*log2(e)
#define TANH_UNSCALE 0.34657359027997264f // ln2/2

__device__ __forceinline__ short cvt_bf16(float f) {
  union { float f; uint32_t u; } x; x.f = f;
  uint32_t r = x.u + 0x7FFFu + ((x.u >> 16) & 1u);  // RNE
  return (short)(r >> 16);
}
__device__ __forceinline__ float bf16_to_f(short s) {
  union { uint32_t u; float f; } x; x.u = ((uint32_t)(uint16_t)s) << 16;
  return x.f;
}

// tanh(x) = 1 - 2/(e^{2x}+1); exp2 form never overflows the denominator.
__device__ __forceinline__ float tanh_fast(float x) {
  float e = __builtin_amdgcn_exp2f(x * TANH_SCALE);
  return 1.0f - 2.0f * __builtin_amdgcn_rcpf(e + 1.0f);
}
// input already scaled by TANH_SCALE
__device__ __forceinline__ float tanh_pre(float xs) {
  float e = __builtin_amdgcn_exp2f(xs);
  return 1.0f - 2.0f * __builtin_amdgcn_rcpf(e + 1.0f);
}

// ---------- fused preprocessing: convert_split | transpose_split(w1) | transpose_cvt(w4) | fb ----
// block ranges: [0,1024) convert, [1024,1280) w1 transpose-split, [1280,1792) w4 transpose,
// [1792,1872) fb. Saves 3 kernel-launch gaps vs separate dispatches.
__global__ __launch_bounds__(256) void k_prep(const float* __restrict__ video,
                                              const float* __restrict__ text,
                                              const float* __restrict__ w1,
                                              const float* __restrict__ w2,
                                              const float* __restrict__ bias,
                                              const float* __restrict__ w4,
                                              short* __restrict__ vhi,
                                              short* __restrict__ vlo,
                                              short* __restrict__ w1h,
                                              short* __restrict__ w1l,
                                              short* __restrict__ w4T,
                                              float* __restrict__ fbuf) {
  __shared__ float tile[32][33];
  int bid = blockIdx.x;
  if (bid < 1024) {
    // f32 -> (hi,lo) bf16 split convert of video, 2,097,152 float4s
    int i = bid * 256 + threadIdx.x;
    for (; i < 2097152; i += 1024 * 256) {
      float4 v = ((const float4*)video)[i];
      bf16x4 h, l;
      h.x = cvt_bf16(v.x); h.y = cvt_bf16(v.y); h.z = cvt_bf16(v.z); h.w = cvt_bf16(v.w);
      l.x = cvt_bf16(v.x - bf16_to_f(h.x));
      l.y = cvt_bf16(v.y - bf16_to_f(h.y));
      l.z = cvt_bf16(v.z - bf16_to_f(h.z));
      l.w = cvt_bf16(v.w - bf16_to_f(h.w));
      ((bf16x4*)vhi)[i] = h;
      ((bf16x4*)vlo)[i] = l;
    }
  } else if (bid < 1280) {
    // w1 (1024x256) -> transposed hi/lo bf16 (256x1024)
    int idx = bid - 1024;
    int r0 = (idx & 31) * 32, c0 = (idx >> 5) * 32;
    int j = threadIdx.x & 31, i0 = threadIdx.x >> 5;
    #pragma unroll
    for (int i = i0; i < 32; i += 8) tile[i][j] = w1[(size_t)(r0 + i) * 256 + c0 + j];
    __syncthreads();
    #pragma unroll
    for (int i = i0; i < 32; i += 8) {
      float v = tile[j][i];
      short h = cvt_bf16(v);
      w1h[(size_t)(c0 + i) * 1024 + r0 + j] = h;
      w1l[(size_t)(c0 + i) * 1024 + r0 + j] = cvt_bf16(v - bf16_to_f(h));
    }
  } else if (bid < 1792) {
    // w4 (1024x500) -> transposed bf16 (512x1024), rows 500..511 zero
    int idx = bid - 1280;
    int r0 = (idx & 31) * 32, c0 = (idx >> 5) * 32;
    int j = threadIdx.x & 31, i0 = threadIdx.x >> 5;
    #pragma unroll
    for (int i = i0; i < 32; i += 8) {
      int c = c0 + j;
      tile[i][j] = (c < 500) ? w4[(size_t)(r0 + i) * 500 + c] : 0.f;
    }
    __syncthreads();
    #pragma unroll
    for (int i = i0; i < 32; i += 8)
      w4T[(size_t)(c0 + i) * 1024 + r0 + j] = cvt_bf16(tile[j][i]);
  } else {
    // fb[b][t][a] = text[b,t,:] . w2[:,a] + bias[a]  (K=300, exact f32)
    int idx = bid - 1792;
    int b = idx & 15, t0 = (idx >> 4) * 8, a = threadIdx.x;
    float acc[8] = {0.f,0.f,0.f,0.f,0.f,0.f,0.f,0.f};
    const float* tp = text + ((size_t)b * 40 + t0) * 300;
    for (int k = 0; k < 300; k++) {
      float wv = w2[k * 256 + a];
      #pragma unroll
      for (int j = 0; j < 8; j++) acc[j] += tp[j * 300 + k] * wv;
    }
    float bv = bias[a];
    #pragma unroll
    for (int j = 0; j < 8; j++)
      fbuf[((size_t)b * 40 + t0 + j) * 256 + a] = acc[j] + bv;
  }
}

// ---------- split-bf16 MFMA GEMM (~f32 precision): C = (Ah+Al) * (Bh+Bl)^T ----------
// round-5 structure (known good): 64x64 tile, 256 thr, grid 512 -> 2 blocks/CU.
__global__ __launch_bounds__(256) void k_gemm_split(const short* __restrict__ Ah,
                                                    const short* __restrict__ Al,
                                                    const short* __restrict__ BTh,
                                                    const short* __restrict__ BTl,
                                                    float* __restrict__ C,
                                                    int K, int ldc) {
  __shared__ __align__(16) short Ash[64][72];
  __shared__ __align__(16) short Asl[64][72];
  __shared__ __align__(16) short Bsh[64][72];
  __shared__ __align__(16) short Bsl[64][72];
  int m0 = blockIdx.x * 64, n0 = blockIdx.y * 64;
  int tid = threadIdx.x, lane = tid & 63, wave = tid >> 6;
  int wm = (wave & 1) * 32, wn = (wave >> 1) * 32;
  int srow = tid >> 3, sseg = (tid & 7) * 8;
  f32x4 acc[2][2];
  #pragma unroll
  for (int i = 0; i < 2; i++)
    #pragma unroll
    for (int j = 0; j < 2; j++) acc[i][j] = (f32x4){0.f, 0.f, 0.f, 0.f};
  int mrow = lane & 15, quad = lane >> 4;

  for (int k0 = 0; k0 < K; k0 += 64) {
    size_t aoff0 = (size_t)(m0 + srow) * K + k0 + sseg;
    size_t aoff1 = aoff0 + (size_t)32 * K;
    size_t boff0 = (size_t)(n0 + srow) * K + k0 + sseg;
    size_t boff1 = boff0 + (size_t)32 * K;
    bf16x8 a0h = *(const bf16x8*)(Ah + aoff0);
    bf16x8 a1h = *(const bf16x8*)(Ah + aoff1);
    bf16x8 a0l = *(const bf16x8*)(Al + aoff0);
    bf16x8 a1l = *(const bf16x8*)(Al + aoff1);
    bf16x8 b0h = *(const bf16x8*)(BTh + boff0);
    bf16x8 b1h = *(const bf16x8*)(BTh + boff1);
    bf16x8 b0l = *(const bf16x8*)(BTl + boff0);
    bf16x8 b1l = *(const bf16x8*)(BTl + boff1);
    __syncthreads();
    *(bf16x8*)&Ash[srow][sseg] = a0h;  *(bf16x8*)&Ash[srow + 32][sseg] = a1h;
    *(bf16x8*)&Asl[srow][sseg] = a0l;  *(bf16x8*)&Asl[srow + 32][sseg] = a1l;
    *(bf16x8*)&Bsh[srow][sseg] = b0h;  *(bf16x8*)&Bsh[srow + 32][sseg] = b1h;
    *(bf16x8*)&Bsl[srow][sseg] = b0l;  *(bf16x8*)&Bsl[srow + 32][sseg] = b1l;
    __syncthreads();
    #pragma unroll
    for (int ks = 0; ks < 2; ks++) {
      int kk = ks * 32 + quad * 8;
      bf16x8 ah[2], al[2], bh[2], bl[2];
      ah[0] = *(const bf16x8*)&Ash[wm + mrow][kk];
      ah[1] = *(const bf16x8*)&Ash[wm + 16 + mrow][kk];
      al[0] = *(const bf16x8*)&Asl[wm + mrow][kk];
      al[1] = *(const bf16x8*)&Asl[wm + 16 + mrow][kk];
      bh[0] = *(const bf16x8*)&Bsh[wn + mrow][kk];
      bh[1] = *(const bf16x8*)&Bsh[wn + 16 + mrow][kk];
      bl[0] = *(const bf16x8*)&Bsl[wn + mrow][kk];
      bl[1] = *(const bf16x8*)&Bsl[wn + 16 + mrow][kk];
      #pragma unroll
      for (int i = 0; i < 2; i++)
        #pragma unroll
        for (int j = 0; j < 2; j++) {
          acc[i][j] = __builtin_amdgcn_mfma_f32_16x16x32_bf16(ah[i], bh[j], acc[i][j], 0, 0, 0);
          acc[i][j] = __builtin_amdgcn_mfma_f32_16x16x32_bf16(ah[i], bl[j], acc[i][j], 0, 0, 0);
          acc[i][j] = __builtin_amdgcn_mfma_f32_16x16x32_bf16(al[i], bh[j], acc[i][j], 0, 0, 0);
        }
    }
  }
  int rbase = quad * 4;
  #pragma unroll
  for (int i = 0; i < 2; i++)
    #pragma unroll
    for (int j = 0; j < 2; j++) {
      int col = n0 + wn + j * 16 + mrow;
      #pragma unroll
      for (int r = 0; r < 4; r++) {
        int row = m0 + wm + i * 16 + rbase + r;
        C[(size_t)row * ldc + col] = acc[i][j][r];
      }
    }
}

// async global->LDS, 16 B per lane; lds base must be wave-uniform (lane i lands at base+16*i)
__device__ __forceinline__ void load_lds16(void* lds, const void* g) {
  __builtin_amdgcn_global_load_lds(
      (const __attribute__((address_space(1))) void*)g,
      (__attribute__((address_space(3))) void*)lds, 16, 0, 0);
}

// ---------- final GEMM, m97-style: 128x64 tile, BK=64, global_load_lds(16B), grid 512 ----------
__global__ __launch_bounds__(256) void k_gemm_f(const short* __restrict__ A,
                                                const short* __restrict__ BT,
                                                const float* __restrict__ bias,
                                                float* __restrict__ C,
                                                int K, int ldc, int nstore) {
  __shared__ __align__(16) short As[128][64];  // 16 KB, unpadded (async-copy layout)
  __shared__ __align__(16) short Bs[64][64];   //  8 KB
  int m0 = blockIdx.x * 128, n0 = blockIdx.y * 64;
  int tid = threadIdx.x, lane = tid & 63, wave = tid >> 6;
  int wm = wave * 32;
  int mrow = lane & 15, quad = lane >> 4;
  int lrow = lane >> 3, lseg = (lane & 7) * 8;

  f32x4 acc[2][4];
  #pragma unroll
  for (int i = 0; i < 2; i++)
    #pragma unroll
    for (int j = 0; j < 4; j++) acc[i][j] = (f32x4){0.f, 0.f, 0.f, 0.f};

  for (int k0 = 0; k0 < K; k0 += 64) {
    __syncthreads();
    #pragma unroll
    for (int i = 0; i < 4; i++) {
      int c = wave * 4 + i;
      load_lds16(&As[c * 8][0], A + (size_t)(m0 + c * 8 + lrow) * K + k0 + lseg);
    }
    #pragma unroll
    for (int i = 0; i < 2; i++) {
      int c = wave * 2 + i;
      load_lds16(&Bs[c * 8][0], BT + (size_t)(n0 + c * 8 + lrow) * K + k0 + lseg);
    }
    __syncthreads();
    #pragma unroll
    for (int ks = 0; ks < 2; ks++) {
      int kk = ks * 32 + quad * 8;
      bf16x8 af[2], bf[4];
      #pragma unroll
      for (int i = 0; i < 2; i++) af[i] = *(const bf16x8*)&As[wm + i * 16 + mrow][kk];
      #pragma unroll
      for (int j = 0; j < 4; j++) bf[j] = *(const bf16x8*)&Bs[j * 16 + mrow][kk];
      #pragma unroll
      for (int i = 0; i < 2; i++)
        #pragma unroll
        for (int j = 0; j < 4; j++)
          acc[i][j] = __builtin_amdgcn_mfma_f32_16x16x32_bf16(af[i], bf[j], acc[i][j], 0, 0, 0);
    }
  }
  int rbase = quad * 4;
  #pragma unroll
  for (int i = 0; i < 2; i++)
    #pragma unroll
    for (int j = 0; j < 4; j++) {
      int col = n0 + j * 16 + mrow;
      if (col < nstore) {
        float bv = bias[col];
        #pragma unroll
        for (int r = 0; r < 4; r++) {
          int row = m0 + wm + i * 16 + rbase + r;
          C[(size_t)row * ldc + col] = acc[i][j][r] + bv;
        }
      }
    }
}

// ---------- fused middle v7: half-wave per row, 5-step butterflies, 8 a/lane ----------
// 512 thr = 8 waves; wave handles rowA=row0+wave (lanes 0-31) and rowB=rowA+8 (lanes 32-63).
// Lane owns 8 consecutive a (a0=(lane&31)*8). Reduction = 5 shfl_xor steps within the half —
// covers BOTH rows in one op stream (200 bpermutes/row-pair vs 480 in v6). fbs reads are
// identical across halves (free 2-way broadcast). Stores are full b128.
__global__ __launch_bounds__(512) void k_middle(const float* __restrict__ e,
                                                const float* __restrict__ fb,
                                                const float* __restrict__ w3,
                                                const float* __restrict__ bias,
                                                short* __restrict__ cont) {
  __shared__ __align__(16) float fbs[40 * 256];  // 40 KB (scaled by TANH_SCALE)
  __shared__ float lg[16][40];
  __shared__ float attn[16][40];
  int tid = threadIdx.x, wave = tid >> 6, lane = tid & 63;
  int la = lane & 31, half = lane >> 5;
  int row0 = blockIdx.x * 16;
  int b = row0 >> 9;          // 512 rows per batch; 16 | 512 so block is batch-pure
  int lgrow = wave + (half ? 8 : 0);
  int myrow = row0 + lgrow;

  const float4* fsrc = (const float4*)(fb + (size_t)b * 40 * 256);
  for (int i = tid; i < 40 * 64; i += 512) {
    float4 v = fsrc[i];
    v.x *= TANH_SCALE; v.y *= TANH_SCALE; v.z *= TANH_SCALE; v.w *= TANH_SCALE;
    ((float4*)fbs)[i] = v;
  }
  __syncthreads();

  int a0 = la * 8;
  const float* erow = e + (size_t)myrow * 256 + a0;
  float4 e0 = *(const float4*)erow;
  float4 e1 = *(const float4*)(erow + 4);
  float4 w30 = *(const float4*)(w3 + a0);
  float4 w31 = *(const float4*)(w3 + a0 + 4);
  float4 bv0 = *(const float4*)(bias + a0);
  float4 bv1 = *(const float4*)(bias + a0 + 4);
  float4 es0, es1;
  es0.x = e0.x * TANH_SCALE; es0.y = e0.y * TANH_SCALE;
  es0.z = e0.z * TANH_SCALE; es0.w = e0.w * TANH_SCALE;
  es1.x = e1.x * TANH_SCALE; es1.y = e1.y * TANH_SCALE;
  es1.z = e1.z * TANH_SCALE; es1.w = e1.w * TANH_SCALE;

  // phase 1: logits; chunks of 4 t -> 4 independent 5-step butterfly chains
  for (int tc = 0; tc < 40; tc += 4) {
    float p[4];
    #pragma unroll
    for (int u = 0; u < 4; u++) {
      const float* fr = &fbs[(tc + u) * 256 + a0];
      float4 f0 = *(const float4*)fr;
      float4 f1 = *(const float4*)(fr + 4);
      p[u] = tanh_pre(es0.x + f0.x) * w30.x + tanh_pre(es0.y + f0.y) * w30.y
           + tanh_pre(es0.z + f0.z) * w30.z + tanh_pre(es0.w + f0.w) * w30.w
           + tanh_pre(es1.x + f1.x) * w31.x + tanh_pre(es1.y + f1.y) * w31.y
           + tanh_pre(es1.z + f1.z) * w31.z + tanh_pre(es1.w + f1.w) * w31.w;
    }
    #pragma unroll
    for (int s = 16; s >= 1; s >>= 1) {
      #pragma unroll
      for (int u = 0; u < 4; u++) p[u] += __shfl_xor(p[u], s, 64);
    }
    if (la == 0) {
      #pragma unroll
      for (int u = 0; u < 4; u++) lg[lgrow][tc + u] = p[u];
    }
  }
  // lg written and read by the same wave -> lgkmcnt ordering suffices, no barrier.

  // phase 2: wave-local softmax per row (full-wave, lanes >= 40 idle via -inf/0)
  auto softmax_row = [&](int r) {
    float x = (lane < 40) ? lg[r][lane] : -3.0e38f;
    float m = x;
    #pragma unroll
    for (int s = 32; s >= 1; s >>= 1) m = fmaxf(m, __shfl_xor(m, s, 64));
    float ex = (lane < 40) ? __builtin_amdgcn_exp2f((x - m) * 1.4426950408889634f) : 0.f;
    float ssum = ex;
    #pragma unroll
    for (int s = 32; s >= 1; s >>= 1) ssum += __shfl_xor(ssum, s, 64);
    if (lane < 40) attn[r][lane] = ex * __builtin_amdgcn_rcpf(ssum);
  };
  softmax_row(wave);
  softmax_row(wave + 8);

  // phase 3: text_attn (8-wide per lane) = (sum_t attn[t]*fbs_scaled[t]) * UNSCALE - bias
  float ac[8] = {0.f,0.f,0.f,0.f,0.f,0.f,0.f,0.f};
  for (int t = 0; t < 40; t++) {
    float w = attn[lgrow][t];  // half-uniform broadcast (2 distinct addrs/wave)
    const float* fr = &fbs[t * 256 + a0];
    float4 f0 = *(const float4*)fr;
    float4 f1 = *(const float4*)(fr + 4);
    ac[0] += w * f0.x; ac[1] += w * f0.y; ac[2] += w * f0.z; ac[3] += w * f0.w;
    ac[4] += w * f1.x; ac[5] += w * f1.y; ac[6] += w * f1.z; ac[7] += w * f1.w;
  }
  float tx[8];
  tx[0] = ac[0] * TANH_UNSCALE - bv0.x; tx[1] = ac[1] * TANH_UNSCALE - bv0.y;
  tx[2] = ac[2] * TANH_UNSCALE - bv0.z; tx[3] = ac[3] * TANH_UNSCALE - bv0.w;
  tx[4] = ac[4] * TANH_UNSCALE - bv1.x; tx[5] = ac[5] * TANH_UNSCALE - bv1.y;
  tx[6] = ac[6] * TANH_UNSCALE - bv1.z; tx[7] = ac[7] * TANH_UNSCALE - bv1.w;
  float ev[8] = {e0.x, e0.y, e0.z, e0.w, e1.x, e1.y, e1.z, e1.w};

  short* crow = cont + (size_t)myrow * 1024 + a0;
  auto st8 = [&](int off, const float* v) {
    bf16x8 pk;
    #pragma unroll
    for (int i = 0; i < 8; i++) pk[i] = cvt_bf16(v[i]);
    *(bf16x8*)(crow + off) = pk;
  };
  float s0[8], s1[8], s2[8], s3[8];
  #pragma unroll
  for (int i = 0; i < 8; i++) {
    s0[i] = tanh_fast(ev[i]);
    s1[i] = tanh_fast(tx[i]);
    s2[i] = tanh_fast(ev[i] * tx[i]);
    s3[i] = tanh_fast(ev[i] - tx[i]);
  }
  st8(0, s0); st8(256, s1); st8(512, s2); st8(768, s3);
}

extern "C" void kernel_launch(void* const* d_in, const int* in_sizes, int n_in,
                              void* d_out, int out_size, void* d_ws, size_t ws_size,
                              hipStream_t stream) {
  const float* video = (const float*)d_in[0];  // 16x512x1024
  const float* text  = (const float*)d_in[1];  // 16x40x300
  const float* w1    = (const float*)d_in[2];  // 1024x256
  const float* w2    = (const float*)d_in[3];  // 300x256
  const float* w3    = (const float*)d_in[4];  // 256
  const float* bias  = (const float*)d_in[5];  // 256
  const float* w4    = (const float*)d_in[6];  // 1024x500
  const float* b4    = (const float*)d_in[7];  // 500
  float* out = (float*)d_out;                  // 16x512x500
  char* ws = (char*)d_ws;

  // workspace layout (bytes)
  short* video_hi = (short*)(ws);              // 8192x1024 bf16 = 16,777,216
  short* video_lo = (short*)(ws + 16777216);   // 8192x1024 bf16 = 16,777,216 (aliased w/ contbuf)
  short* contbuf  = (short*)(ws + 16777216);   // dead until after e-GEMM consumes video_lo
  short* w1T_hi   = (short*)(ws + 33554432);   // 256x1024 bf16 = 524,288
  short* w1T_lo   = (short*)(ws + 34078720);   // 256x1024 bf16 = 524,288
  short* w4T      = (short*)(ws + 34603008);   // 512x1024 bf16 = 1,048,576 (rows 500..511 zero)
  float* fbuf     = (float*)(ws + 35651584);   // 16x40x256 f32 = 655,360 (f + bias)
  float* ebuf     = (float*)(ws + 36306944);   // 8192x256 f32  = 8,388,608

  k_prep<<<1872, 256, 0, stream>>>(video, text, w1, w2, bias, w4,
                                   video_hi, video_lo, w1T_hi, w1T_lo, w4T, fbuf);
  k_gemm_split<<<dim3(128, 4), 256, 0, stream>>>(video_hi, video_lo, w1T_hi, w1T_lo,
                                                 ebuf, 1024, 256);
  k_middle<<<512, 512, 0, stream>>>(ebuf, fbuf, w3, bias, contbuf);
  k_gemm_f<<<dim3(64, 8), 256, 0, stream>>>(contbuf, w4T, b4, out, 1024, 500, 500);
}

// Round 8
// 177.522 us; speedup vs baseline: 1.3406x; 1.1049x over previous
//
#include <hip/hip_runtime.h>
#include <hip/hip_bf16.h>
#include <cstdint>

typedef __attribute__((ext_vector_type(8))) short bf16x8;
typedef __attribute__((ext_vector_type(4))) short bf16x4;
typedef __attribute__((ext_vector_type(4))) float f32x4;

#define TANH_SCALE 2.8853900817779268f    // 2*log2(e)
#define TANH_UNSCALE 0.34657359027997264f // ln2/2

__device__ __forceinline__ short cvt_bf16(float f) {
  union { float f; uint32_t u; } x; x.f = f;
  uint32_t r = x.u + 0x7FFFu + ((x.u >> 16) & 1u);  // RNE
  return (short)(r >> 16);
}
__device__ __forceinline__ float bf16_to_f(short s) {
  union { uint32_t u; float f; } x; x.u = ((uint32_t)(uint16_t)s) << 16;
  return x.f;
}

// tanh(x) = 1 - 2/(e^{2x}+1); exp2 form never overflows the denominator.
__device__ __forceinline__ float tanh_fast(float x) {
  float e = __builtin_amdgcn_exp2f(x * TANH_SCALE);
  return 1.0f - 2.0f * __builtin_amdgcn_rcpf(e + 1.0f);
}
// input already scaled by TANH_SCALE
__device__ __forceinline__ float tanh_pre(float xs) {
  float e = __builtin_amdgcn_exp2f(xs);
  return 1.0f - 2.0f * __builtin_amdgcn_rcpf(e + 1.0f);
}

// ---------- fused preprocessing (all streaming, no long dep chains) ----------
// [0,1024)    video f32 -> hi/lo bf16 split
// [1024,1280) w1 (1024x256) -> transposed hi/lo bf16 (256x1024)
// [1280,1792) w4 (1024x500) -> transposed bf16 (512x1024), pad rows 500..511 = 0
// [1792,1952) text (640x300) -> hi/lo bf16, K zero-padded to 320 (640x320)
// [1952,2032) w2 (300x256) -> transposed hi/lo bf16 (256x320), pad k 300..319 = 0
__global__ __launch_bounds__(256) void k_prep(const float* __restrict__ video,
                                              const float* __restrict__ text,
                                              const float* __restrict__ w1,
                                              const float* __restrict__ w2,
                                              const float* __restrict__ w4,
                                              short* __restrict__ vhi,
                                              short* __restrict__ vlo,
                                              short* __restrict__ w1h,
                                              short* __restrict__ w1l,
                                              short* __restrict__ w4T,
                                              short* __restrict__ th,
                                              short* __restrict__ tl,
                                              short* __restrict__ w2h,
                                              short* __restrict__ w2l) {
  __shared__ float tile[32][33];
  int bid = blockIdx.x;
  if (bid < 1024) {
    int i = bid * 256 + threadIdx.x;
    for (; i < 2097152; i += 1024 * 256) {
      float4 v = ((const float4*)video)[i];
      bf16x4 h, l;
      h.x = cvt_bf16(v.x); h.y = cvt_bf16(v.y); h.z = cvt_bf16(v.z); h.w = cvt_bf16(v.w);
      l.x = cvt_bf16(v.x - bf16_to_f(h.x));
      l.y = cvt_bf16(v.y - bf16_to_f(h.y));
      l.z = cvt_bf16(v.z - bf16_to_f(h.z));
      l.w = cvt_bf16(v.w - bf16_to_f(h.w));
      ((bf16x4*)vhi)[i] = h;
      ((bf16x4*)vlo)[i] = l;
    }
  } else if (bid < 1280) {
    int idx = bid - 1024;
    int r0 = (idx & 31) * 32, c0 = (idx >> 5) * 32;
    int j = threadIdx.x & 31, i0 = threadIdx.x >> 5;
    #pragma unroll
    for (int i = i0; i < 32; i += 8) tile[i][j] = w1[(size_t)(r0 + i) * 256 + c0 + j];
    __syncthreads();
    #pragma unroll
    for (int i = i0; i < 32; i += 8) {
      float v = tile[j][i];
      short h = cvt_bf16(v);
      w1h[(size_t)(c0 + i) * 1024 + r0 + j] = h;
      w1l[(size_t)(c0 + i) * 1024 + r0 + j] = cvt_bf16(v - bf16_to_f(h));
    }
  } else if (bid < 1792) {
    int idx = bid - 1280;
    int r0 = (idx & 31) * 32, c0 = (idx >> 5) * 32;
    int j = threadIdx.x & 31, i0 = threadIdx.x >> 5;
    #pragma unroll
    for (int i = i0; i < 32; i += 8) {
      int c = c0 + j;
      tile[i][j] = (c < 500) ? w4[(size_t)(r0 + i) * 500 + c] : 0.f;
    }
    __syncthreads();
    #pragma unroll
    for (int i = i0; i < 32; i += 8)
      w4T[(size_t)(c0 + i) * 1024 + r0 + j] = cvt_bf16(tile[j][i]);
  } else if (bid < 1952) {
    // text split+pad: 4 rows per block, 64 lanes per row
    int idx = bid - 1792;
    int row = idx * 4 + (threadIdx.x >> 6);
    int cl = threadIdx.x & 63;
    const float* trow = text + (size_t)row * 300;
    short* hrow = th + (size_t)row * 320;
    short* lrow = tl + (size_t)row * 320;
    #pragma unroll
    for (int c0 = 0; c0 < 320; c0 += 64) {
      int c = c0 + cl;
      float v = (c < 300) ? trow[c] : 0.f;
      short h = cvt_bf16(v);
      hrow[c] = h;
      lrow[c] = cvt_bf16(v - bf16_to_f(h));
    }
  } else {
    // w2 transpose-split: w2T[c][r] = w2[r][c], r padded to 320
    int idx = bid - 1952;                 // 0..79
    int rt = idx % 10, ct = idx / 10;
    int r0 = rt * 32, c0 = ct * 32;
    int j = threadIdx.x & 31, i0 = threadIdx.x >> 5;
    #pragma unroll
    for (int i = i0; i < 32; i += 8) {
      int r = r0 + i;
      tile[i][j] = (r < 300) ? w2[(size_t)r * 256 + c0 + j] : 0.f;
    }
    __syncthreads();
    #pragma unroll
    for (int i = i0; i < 32; i += 8) {
      float v = tile[j][i];               // = w2[r0+j][c0+i]
      short h = cvt_bf16(v);
      w2h[(size_t)(c0 + i) * 320 + r0 + j] = h;
      w2l[(size_t)(c0 + i) * 320 + r0 + j] = cvt_bf16(v - bf16_to_f(h));
    }
  }
}

// ---------- split-bf16 MFMA GEMM (~f32 precision): C = (Ah+Al) * (Bh+Bl)^T ----------
// 64x64 tile, 256 thr. Used for e (K=1024) and fb (K=320).
__global__ __launch_bounds__(256) void k_gemm_split(const short* __restrict__ Ah,
                                                    const short* __restrict__ Al,
                                                    const short* __restrict__ BTh,
                                                    const short* __restrict__ BTl,
                                                    float* __restrict__ C,
                                                    int K, int ldc) {
  __shared__ __align__(16) short Ash[64][72];
  __shared__ __align__(16) short Asl[64][72];
  __shared__ __align__(16) short Bsh[64][72];
  __shared__ __align__(16) short Bsl[64][72];
  int m0 = blockIdx.x * 64, n0 = blockIdx.y * 64;
  int tid = threadIdx.x, lane = tid & 63, wave = tid >> 6;
  int wm = (wave & 1) * 32, wn = (wave >> 1) * 32;
  int srow = tid >> 3, sseg = (tid & 7) * 8;
  f32x4 acc[2][2];
  #pragma unroll
  for (int i = 0; i < 2; i++)
    #pragma unroll
    for (int j = 0; j < 2; j++) acc[i][j] = (f32x4){0.f, 0.f, 0.f, 0.f};
  int mrow = lane & 15, quad = lane >> 4;

  for (int k0 = 0; k0 < K; k0 += 64) {
    size_t aoff0 = (size_t)(m0 + srow) * K + k0 + sseg;
    size_t aoff1 = aoff0 + (size_t)32 * K;
    size_t boff0 = (size_t)(n0 + srow) * K + k0 + sseg;
    size_t boff1 = boff0 + (size_t)32 * K;
    bf16x8 a0h = *(const bf16x8*)(Ah + aoff0);
    bf16x8 a1h = *(const bf16x8*)(Ah + aoff1);
    bf16x8 a0l = *(const bf16x8*)(Al + aoff0);
    bf16x8 a1l = *(const bf16x8*)(Al + aoff1);
    bf16x8 b0h = *(const bf16x8*)(BTh + boff0);
    bf16x8 b1h = *(const bf16x8*)(BTh + boff1);
    bf16x8 b0l = *(const bf16x8*)(BTl + boff0);
    bf16x8 b1l = *(const bf16x8*)(BTl + boff1);
    __syncthreads();
    *(bf16x8*)&Ash[srow][sseg] = a0h;  *(bf16x8*)&Ash[srow + 32][sseg] = a1h;
    *(bf16x8*)&Asl[srow][sseg] = a0l;  *(bf16x8*)&Asl[srow + 32][sseg] = a1l;
    *(bf16x8*)&Bsh[srow][sseg] = b0h;  *(bf16x8*)&Bsh[srow + 32][sseg] = b1h;
    *(bf16x8*)&Bsl[srow][sseg] = b0l;  *(bf16x8*)&Bsl[srow + 32][sseg] = b1l;
    __syncthreads();
    #pragma unroll
    for (int ks = 0; ks < 2; ks++) {
      int kk = ks * 32 + quad * 8;
      bf16x8 ah[2], al[2], bh[2], bl[2];
      ah[0] = *(const bf16x8*)&Ash[wm + mrow][kk];
      ah[1] = *(const bf16x8*)&Ash[wm + 16 + mrow][kk];
      al[0] = *(const bf16x8*)&Asl[wm + mrow][kk];
      al[1] = *(const bf16x8*)&Asl[wm + 16 + mrow][kk];
      bh[0] = *(const bf16x8*)&Bsh[wn + mrow][kk];
      bh[1] = *(const bf16x8*)&Bsh[wn + 16 + mrow][kk];
      bl[0] = *(const bf16x8*)&Bsl[wn + mrow][kk];
      bl[1] = *(const bf16x8*)&Bsl[wn + 16 + mrow][kk];
      #pragma unroll
      for (int i = 0; i < 2; i++)
        #pragma unroll
        for (int j = 0; j < 2; j++) {
          acc[i][j] = __builtin_amdgcn_mfma_f32_16x16x32_bf16(ah[i], bh[j], acc[i][j], 0, 0, 0);
          acc[i][j] = __builtin_amdgcn_mfma_f32_16x16x32_bf16(ah[i], bl[j], acc[i][j], 0, 0, 0);
          acc[i][j] = __builtin_amdgcn_mfma_f32_16x16x32_bf16(al[i], bh[j], acc[i][j], 0, 0, 0);
        }
    }
  }
  int rbase = quad * 4;
  #pragma unroll
  for (int i = 0; i < 2; i++)
    #pragma unroll
    for (int j = 0; j < 2; j++) {
      int col = n0 + wn + j * 16 + mrow;
      #pragma unroll
      for (int r = 0; r < 4; r++) {
        int row = m0 + wm + i * 16 + rbase + r;
        C[(size_t)row * ldc + col] = acc[i][j][r];
      }
    }
}

// async global->LDS, 16 B per lane; lds base must be wave-uniform (lane i lands at base+16*i)
__device__ __forceinline__ void load_lds16(void* lds, const void* g) {
  __builtin_amdgcn_global_load_lds(
      (const __attribute__((address_space(1))) void*)g,
      (__attribute__((address_space(3))) void*)lds, 16, 0, 0);
}

// ---------- final GEMM, m97-style: 128x64 tile, BK=64, global_load_lds(16B) ----------
__global__ __launch_bounds__(256) void k_gemm_f(const short* __restrict__ A,
                                                const short* __restrict__ BT,
                                                const float* __restrict__ bias,
                                                float* __restrict__ C,
                                                int K, int ldc, int nstore) {
  __shared__ __align__(16) short As[128][64];  // 16 KB, unpadded (async-copy layout)
  __shared__ __align__(16) short Bs[64][64];   //  8 KB
  int m0 = blockIdx.x * 128, n0 = blockIdx.y * 64;
  int tid = threadIdx.x, lane = tid & 63, wave = tid >> 6;
  int wm = wave * 32;
  int mrow = lane & 15, quad = lane >> 4;
  int lrow = lane >> 3, lseg = (lane & 7) * 8;

  f32x4 acc[2][4];
  #pragma unroll
  for (int i = 0; i < 2; i++)
    #pragma unroll
    for (int j = 0; j < 4; j++) acc[i][j] = (f32x4){0.f, 0.f, 0.f, 0.f};

  for (int k0 = 0; k0 < K; k0 += 64) {
    __syncthreads();
    #pragma unroll
    for (int i = 0; i < 4; i++) {
      int c = wave * 4 + i;
      load_lds16(&As[c * 8][0], A + (size_t)(m0 + c * 8 + lrow) * K + k0 + lseg);
    }
    #pragma unroll
    for (int i = 0; i < 2; i++) {
      int c = wave * 2 + i;
      load_lds16(&Bs[c * 8][0], BT + (size_t)(n0 + c * 8 + lrow) * K + k0 + lseg);
    }
    __syncthreads();
    #pragma unroll
    for (int ks = 0; ks < 2; ks++) {
      int kk = ks * 32 + quad * 8;
      bf16x8 af[2], bf[4];
      #pragma unroll
      for (int i = 0; i < 2; i++) af[i] = *(const bf16x8*)&As[wm + i * 16 + mrow][kk];
      #pragma unroll
      for (int j = 0; j < 4; j++) bf[j] = *(const bf16x8*)&Bs[j * 16 + mrow][kk];
      #pragma unroll
      for (int i = 0; i < 2; i++)
        #pragma unroll
        for (int j = 0; j < 4; j++)
          acc[i][j] = __builtin_amdgcn_mfma_f32_16x16x32_bf16(af[i], bf[j], acc[i][j], 0, 0, 0);
    }
  }
  int rbase = quad * 4;
  #pragma unroll
  for (int i = 0; i < 2; i++)
    #pragma unroll
    for (int j = 0; j < 4; j++) {
      int col = n0 + j * 16 + mrow;
      if (col < nstore) {
        float bv = bias[col];
        #pragma unroll
        for (int r = 0; r < 4; r++) {
          int row = m0 + wm + i * 16 + rbase + r;
          C[(size_t)row * ldc + col] = acc[i][j][r] + bv;
        }
      }
    }
}

// ---------- fused middle v8: half-wave per row; fbuf now holds f (bias added in staging) ----------
__global__ __launch_bounds__(512) void k_middle(const float* __restrict__ e,
                                                const float* __restrict__ fb,
                                                const float* __restrict__ w3,
                                                const float* __restrict__ bias,
                                                short* __restrict__ cont) {
  __shared__ __align__(16) float fbs[40 * 256];  // 40 KB: (f+bias)*TANH_SCALE
  __shared__ float lg[16][40];
  __shared__ float attn[16][40];
  int tid = threadIdx.x, wave = tid >> 6, lane = tid & 63;
  int la = lane & 31, half = lane >> 5;
  int row0 = blockIdx.x * 16;
  int b = row0 >> 9;          // 512 rows per batch; 16 | 512 so block is batch-pure
  int lgrow = wave + (half ? 8 : 0);
  int myrow = row0 + lgrow;

  const float4* fsrc = (const float4*)(fb + (size_t)b * 40 * 256);
  const float4* bias4 = (const float4*)bias;
  for (int i = tid; i < 40 * 64; i += 512) {
    float4 v = fsrc[i];
    float4 bb = bias4[i & 63];
    v.x = (v.x + bb.x) * TANH_SCALE; v.y = (v.y + bb.y) * TANH_SCALE;
    v.z = (v.z + bb.z) * TANH_SCALE; v.w = (v.w + bb.w) * TANH_SCALE;
    ((float4*)fbs)[i] = v;
  }
  __syncthreads();

  int a0 = la * 8;
  const float* erow = e + (size_t)myrow * 256 + a0;
  float4 e0 = *(const float4*)erow;
  float4 e1 = *(const float4*)(erow + 4);
  float4 w30 = *(const float4*)(w3 + a0);
  float4 w31 = *(const float4*)(w3 + a0 + 4);
  float4 bv0 = *(const float4*)(bias + a0);
  float4 bv1 = *(const float4*)(bias + a0 + 4);
  float4 es0, es1;
  es0.x = e0.x * TANH_SCALE; es0.y = e0.y * TANH_SCALE;
  es0.z = e0.z * TANH_SCALE; es0.w = e0.w * TANH_SCALE;
  es1.x = e1.x * TANH_SCALE; es1.y = e1.y * TANH_SCALE;
  es1.z = e1.z * TANH_SCALE; es1.w = e1.w * TANH_SCALE;

  // phase 1: logits; chunks of 4 t -> 4 independent 5-step butterfly chains
  for (int tc = 0; tc < 40; tc += 4) {
    float p[4];
    #pragma unroll
    for (int u = 0; u < 4; u++) {
      const float* fr = &fbs[(tc + u) * 256 + a0];
      float4 f0 = *(const float4*)fr;
      float4 f1 = *(const float4*)(fr + 4);
      p[u] = tanh_pre(es0.x + f0.x) * w30.x + tanh_pre(es0.y + f0.y) * w30.y
           + tanh_pre(es0.z + f0.z) * w30.z + tanh_pre(es0.w + f0.w) * w30.w
           + tanh_pre(es1.x + f1.x) * w31.x + tanh_pre(es1.y + f1.y) * w31.y
           + tanh_pre(es1.z + f1.z) * w31.z + tanh_pre(es1.w + f1.w) * w31.w;
    }
    #pragma unroll
    for (int s = 16; s >= 1; s >>= 1) {
      #pragma unroll
      for (int u = 0; u < 4; u++) p[u] += __shfl_xor(p[u], s, 64);
    }
    if (la == 0) {
      #pragma unroll
      for (int u = 0; u < 4; u++) lg[lgrow][tc + u] = p[u];
    }
  }

  // phase 2: wave-local softmax per row
  auto softmax_row = [&](int r) {
    float x = (lane < 40) ? lg[r][lane] : -3.0e38f;
    float m = x;
    #pragma unroll
    for (int s = 32; s >= 1; s >>= 1) m = fmaxf(m, __shfl_xor(m, s, 64));
    float ex = (lane < 40) ? __builtin_amdgcn_exp2f((x - m) * 1.4426950408889634f) : 0.f;
    float ssum = ex;
    #pragma unroll
    for (int s = 32; s >= 1; s >>= 1) ssum += __shfl_xor(ssum, s, 64);
    if (lane < 40) attn[r][lane] = ex * __builtin_amdgcn_rcpf(ssum);
  };
  softmax_row(wave);
  softmax_row(wave + 8);

  // phase 3: text_attn (8-wide per lane) = (sum_t attn[t]*fbs_scaled[t]) * UNSCALE - bias
  float ac[8] = {0.f,0.f,0.f,0.f,0.f,0.f,0.f,0.f};
  for (int t = 0; t < 40; t++) {
    float w = attn[lgrow][t];
    const float* fr = &fbs[t * 256 + a0];
    float4 f0 = *(const float4*)fr;
    float4 f1 = *(const float4*)(fr + 4);
    ac[0] += w * f0.x; ac[1] += w * f0.y; ac[2] += w * f0.z; ac[3] += w * f0.w;
    ac[4] += w * f1.x; ac[5] += w * f1.y; ac[6] += w * f1.z; ac[7] += w * f1.w;
  }
  float tx[8];
  tx[0] = ac[0] * TANH_UNSCALE - bv0.x; tx[1] = ac[1] * TANH_UNSCALE - bv0.y;
  tx[2] = ac[2] * TANH_UNSCALE - bv0.z; tx[3] = ac[3] * TANH_UNSCALE - bv0.w;
  tx[4] = ac[4] * TANH_UNSCALE - bv1.x; tx[5] = ac[5] * TANH_UNSCALE - bv1.y;
  tx[6] = ac[6] * TANH_UNSCALE - bv1.z; tx[7] = ac[7] * TANH_UNSCALE - bv1.w;
  float ev[8] = {e0.x, e0.y, e0.z, e0.w, e1.x, e1.y, e1.z, e1.w};

  short* crow = cont + (size_t)myrow * 1024 + a0;
  auto st8 = [&](int off, const float* v) {
    bf16x8 pk;
    #pragma unroll
    for (int i = 0; i < 8; i++) pk[i] = cvt_bf16(v[i]);
    *(bf16x8*)(crow + off) = pk;
  };
  float s0[8], s1[8], s2[8], s3[8];
  #pragma unroll
  for (int i = 0; i < 8; i++) {
    s0[i] = tanh_fast(ev[i]);
    s1[i] = tanh_fast(tx[i]);
    s2[i] = tanh_fast(ev[i] * tx[i]);
    s3[i] = tanh_fast(ev[i] - tx[i]);
  }
  st8(0, s0); st8(256, s1); st8(512, s2); st8(768, s3);
}

extern "C" void kernel_launch(void* const* d_in, const int* in_sizes, int n_in,
                              void* d_out, int out_size, void* d_ws, size_t ws_size,
                              hipStream_t stream) {
  const float* video = (const float*)d_in[0];  // 16x512x1024
  const float* text  = (const float*)d_in[1];  // 16x40x300
  const float* w1    = (const float*)d_in[2];  // 1024x256
  const float* w2    = (const float*)d_in[3];  // 300x256
  const float* w3    = (const float*)d_in[4];  // 256
  const float* bias  = (const float*)d_in[5];  // 256
  const float* w4    = (const float*)d_in[6];  // 1024x500
  const float* b4    = (const float*)d_in[7];  // 500
  float* out = (float*)d_out;                  // 16x512x500
  char* ws = (char*)d_ws;

  // workspace layout (bytes)
  short* video_hi = (short*)(ws);              // 8192x1024 bf16 = 16,777,216
  short* video_lo = (short*)(ws + 16777216);   // 8192x1024 bf16 (aliased w/ contbuf)
  short* contbuf  = (short*)(ws + 16777216);   // dead until after e-GEMM consumes video_lo
  short* w1T_hi   = (short*)(ws + 33554432);   // 256x1024 bf16 = 524,288
  short* w1T_lo   = (short*)(ws + 34078720);   // 256x1024 bf16 = 524,288
  short* w4T      = (short*)(ws + 34603008);   // 512x1024 bf16 = 1,048,576
  float* fbuf     = (float*)(ws + 35651584);   // 16x40x256 f32 = 655,360 (f only)
  float* ebuf     = (float*)(ws + 36306944);   // 8192x256 f32  = 8,388,608
  // text/w2 split buffers alias the ebuf region (dead until e-GEMM, which runs after fb-GEMM)
  short* text_hi  = (short*)(ws + 36306944);             // 640x320 bf16 = 409,600
  short* text_lo  = (short*)(ws + 36306944 + 409600);    // 640x320 bf16 = 409,600
  short* w2T_hi   = (short*)(ws + 36306944 + 819200);    // 256x320 bf16 = 204,800
  short* w2T_lo   = (short*)(ws + 36306944 + 1024000);   // 256x320 bf16 = 204,800

  k_prep<<<2032, 256, 0, stream>>>(video, text, w1, w2, w4,
                                   video_hi, video_lo, w1T_hi, w1T_lo, w4T,
                                   text_hi, text_lo, w2T_hi, w2T_lo);
  // fb = text @ w2  (M=640, N=256, K=320), ~f32 precision
  k_gemm_split<<<dim3(10, 4), 256, 0, stream>>>(text_hi, text_lo, w2T_hi, w2T_lo,
                                                fbuf, 320, 256);
  // e = video @ w1  (M=8192, N=256, K=1024); overwrites ebuf region (text/w2 bufs now dead)
  k_gemm_split<<<dim3(128, 4), 256, 0, stream>>>(video_hi, video_lo, w1T_hi, w1T_lo,
                                                 ebuf, 1024, 256);
  k_middle<<<512, 512, 0, stream>>>(ebuf, fbuf, w3, bias, contbuf);
  k_gemm_f<<<dim3(64, 8), 256, 0, stream>>>(contbuf, w4T, b4, out, 1024, 500, 500);
}

// Round 9
// 174.500 us; speedup vs baseline: 1.3638x; 1.0173x over previous
//
#include <hip/hip_runtime.h>
#include <hip/hip_bf16.h>
#include <cstdint>

typedef __attribute__((ext_vector_type(8))) short bf16x8;
typedef __attribute__((ext_vector_type(4))) short bf16x4;
typedef __attribute__((ext_vector_type(4))) float f32x4;

#define TANH_SCALE 2.8853900817779268f    // 2*log2(e)
#define TANH_UNSCALE 0.34657359027997264f // ln2/2

__device__ __forceinline__ short cvt_bf16(float f) {
  union { float f; uint32_t u; } x; x.f = f;
  uint32_t r = x.u + 0x7FFFu + ((x.u >> 16) & 1u);  // RNE
  return (short)(r >> 16);
}
__device__ __forceinline__ float bf16_to_f(short s) {
  union { uint32_t u; float f; } x; x.u = ((uint32_t)(uint16_t)s) << 16;
  return x.f;
}

// tanh(x) = 1 - 2/(e^{2x}+1); exp2 form never overflows the denominator.
__device__ __forceinline__ float tanh_fast(float x) {
  float e = __builtin_amdgcn_exp2f(x * TANH_SCALE);
  return 1.0f - 2.0f * __builtin_amdgcn_rcpf(e + 1.0f);
}
// input already scaled by TANH_SCALE
__device__ __forceinline__ float tanh_pre(float xs) {
  float e = __builtin_amdgcn_exp2f(xs);
  return 1.0f - 2.0f * __builtin_amdgcn_rcpf(e + 1.0f);
}

// ---------- fused preprocessing (all streaming, no long dep chains) ----------
__global__ __launch_bounds__(256) void k_prep(const float* __restrict__ video,
                                              const float* __restrict__ text,
                                              const float* __restrict__ w1,
                                              const float* __restrict__ w2,
                                              const float* __restrict__ w4,
                                              short* __restrict__ vhi,
                                              short* __restrict__ vlo,
                                              short* __restrict__ w1h,
                                              short* __restrict__ w1l,
                                              short* __restrict__ w4T,
                                              short* __restrict__ th,
                                              short* __restrict__ tl,
                                              short* __restrict__ w2h,
                                              short* __restrict__ w2l) {
  __shared__ float tile[32][33];
  int bid = blockIdx.x;
  if (bid < 1024) {
    int i = bid * 256 + threadIdx.x;
    for (; i < 2097152; i += 1024 * 256) {
      float4 v = ((const float4*)video)[i];
      bf16x4 h, l;
      h.x = cvt_bf16(v.x); h.y = cvt_bf16(v.y); h.z = cvt_bf16(v.z); h.w = cvt_bf16(v.w);
      l.x = cvt_bf16(v.x - bf16_to_f(h.x));
      l.y = cvt_bf16(v.y - bf16_to_f(h.y));
      l.z = cvt_bf16(v.z - bf16_to_f(h.z));
      l.w = cvt_bf16(v.w - bf16_to_f(h.w));
      ((bf16x4*)vhi)[i] = h;
      ((bf16x4*)vlo)[i] = l;
    }
  } else if (bid < 1280) {
    int idx = bid - 1024;
    int r0 = (idx & 31) * 32, c0 = (idx >> 5) * 32;
    int j = threadIdx.x & 31, i0 = threadIdx.x >> 5;
    #pragma unroll
    for (int i = i0; i < 32; i += 8) tile[i][j] = w1[(size_t)(r0 + i) * 256 + c0 + j];
    __syncthreads();
    #pragma unroll
    for (int i = i0; i < 32; i += 8) {
      float v = tile[j][i];
      short h = cvt_bf16(v);
      w1h[(size_t)(c0 + i) * 1024 + r0 + j] = h;
      w1l[(size_t)(c0 + i) * 1024 + r0 + j] = cvt_bf16(v - bf16_to_f(h));
    }
  } else if (bid < 1792) {
    int idx = bid - 1280;
    int r0 = (idx & 31) * 32, c0 = (idx >> 5) * 32;
    int j = threadIdx.x & 31, i0 = threadIdx.x >> 5;
    #pragma unroll
    for (int i = i0; i < 32; i += 8) {
      int c = c0 + j;
      tile[i][j] = (c < 500) ? w4[(size_t)(r0 + i) * 500 + c] : 0.f;
    }
    __syncthreads();
    #pragma unroll
    for (int i = i0; i < 32; i += 8)
      w4T[(size_t)(c0 + i) * 1024 + r0 + j] = cvt_bf16(tile[j][i]);
  } else if (bid < 1952) {
    // text split+pad: 4 rows per block, 64 lanes per row
    int idx = bid - 1792;
    int row = idx * 4 + (threadIdx.x >> 6);
    int cl = threadIdx.x & 63;
    const float* trow = text + (size_t)row * 300;
    short* hrow = th + (size_t)row * 320;
    short* lrow = tl + (size_t)row * 320;
    #pragma unroll
    for (int c0 = 0; c0 < 320; c0 += 64) {
      int c = c0 + cl;
      float v = (c < 300) ? trow[c] : 0.f;
      short h = cvt_bf16(v);
      hrow[c] = h;
      lrow[c] = cvt_bf16(v - bf16_to_f(h));
    }
  } else {
    // w2 transpose-split: w2T[c][r] = w2[r][c], r padded to 320
    int idx = bid - 1952;                 // 0..79
    int rt = idx % 10, ct = idx / 10;
    int r0 = rt * 32, c0 = ct * 32;
    int j = threadIdx.x & 31, i0 = threadIdx.x >> 5;
    #pragma unroll
    for (int i = i0; i < 32; i += 8) {
      int r = r0 + i;
      tile[i][j] = (r < 300) ? w2[(size_t)r * 256 + c0 + j] : 0.f;
    }
    __syncthreads();
    #pragma unroll
    for (int i = i0; i < 32; i += 8) {
      float v = tile[j][i];               // = w2[r0+j][c0+i]
      short h = cvt_bf16(v);
      w2h[(size_t)(c0 + i) * 320 + r0 + j] = h;
      w2l[(size_t)(c0 + i) * 320 + r0 + j] = cvt_bf16(v - bf16_to_f(h));
    }
  }
}

// ---------- split-bf16 MFMA GEMM, 64x64 VALU-staged (used only for tiny fb GEMM) ----------
__global__ __launch_bounds__(256) void k_gemm_split(const short* __restrict__ Ah,
                                                    const short* __restrict__ Al,
                                                    const short* __restrict__ BTh,
                                                    const short* __restrict__ BTl,
                                                    float* __restrict__ C,
                                                    int K, int ldc) {
  __shared__ __align__(16) short Ash[64][72];
  __shared__ __align__(16) short Asl[64][72];
  __shared__ __align__(16) short Bsh[64][72];
  __shared__ __align__(16) short Bsl[64][72];
  int m0 = blockIdx.x * 64, n0 = blockIdx.y * 64;
  int tid = threadIdx.x, lane = tid & 63, wave = tid >> 6;
  int wm = (wave & 1) * 32, wn = (wave >> 1) * 32;
  int srow = tid >> 3, sseg = (tid & 7) * 8;
  f32x4 acc[2][2];
  #pragma unroll
  for (int i = 0; i < 2; i++)
    #pragma unroll
    for (int j = 0; j < 2; j++) acc[i][j] = (f32x4){0.f, 0.f, 0.f, 0.f};
  int mrow = lane & 15, quad = lane >> 4;

  for (int k0 = 0; k0 < K; k0 += 64) {
    size_t aoff0 = (size_t)(m0 + srow) * K + k0 + sseg;
    size_t aoff1 = aoff0 + (size_t)32 * K;
    size_t boff0 = (size_t)(n0 + srow) * K + k0 + sseg;
    size_t boff1 = boff0 + (size_t)32 * K;
    bf16x8 a0h = *(const bf16x8*)(Ah + aoff0);
    bf16x8 a1h = *(const bf16x8*)(Ah + aoff1);
    bf16x8 a0l = *(const bf16x8*)(Al + aoff0);
    bf16x8 a1l = *(const bf16x8*)(Al + aoff1);
    bf16x8 b0h = *(const bf16x8*)(BTh + boff0);
    bf16x8 b1h = *(const bf16x8*)(BTh + boff1);
    bf16x8 b0l = *(const bf16x8*)(BTl + boff0);
    bf16x8 b1l = *(const bf16x8*)(BTl + boff1);
    __syncthreads();
    *(bf16x8*)&Ash[srow][sseg] = a0h;  *(bf16x8*)&Ash[srow + 32][sseg] = a1h;
    *(bf16x8*)&Asl[srow][sseg] = a0l;  *(bf16x8*)&Asl[srow + 32][sseg] = a1l;
    *(bf16x8*)&Bsh[srow][sseg] = b0h;  *(bf16x8*)&Bsh[srow + 32][sseg] = b1h;
    *(bf16x8*)&Bsl[srow][sseg] = b0l;  *(bf16x8*)&Bsl[srow + 32][sseg] = b1l;
    __syncthreads();
    #pragma unroll
    for (int ks = 0; ks < 2; ks++) {
      int kk = ks * 32 + quad * 8;
      bf16x8 ah[2], al[2], bh[2], bl[2];
      ah[0] = *(const bf16x8*)&Ash[wm + mrow][kk];
      ah[1] = *(const bf16x8*)&Ash[wm + 16 + mrow][kk];
      al[0] = *(const bf16x8*)&Asl[wm + mrow][kk];
      al[1] = *(const bf16x8*)&Asl[wm + 16 + mrow][kk];
      bh[0] = *(const bf16x8*)&Bsh[wn + mrow][kk];
      bh[1] = *(const bf16x8*)&Bsh[wn + 16 + mrow][kk];
      bl[0] = *(const bf16x8*)&Bsl[wn + mrow][kk];
      bl[1] = *(const bf16x8*)&Bsl[wn + 16 + mrow][kk];
      #pragma unroll
      for (int i = 0; i < 2; i++)
        #pragma unroll
        for (int j = 0; j < 2; j++) {
          acc[i][j] = __builtin_amdgcn_mfma_f32_16x16x32_bf16(ah[i], bh[j], acc[i][j], 0, 0, 0);
          acc[i][j] = __builtin_amdgcn_mfma_f32_16x16x32_bf16(ah[i], bl[j], acc[i][j], 0, 0, 0);
          acc[i][j] = __builtin_amdgcn_mfma_f32_16x16x32_bf16(al[i], bh[j], acc[i][j], 0, 0, 0);
        }
    }
  }
  int rbase = quad * 4;
  #pragma unroll
  for (int i = 0; i < 2; i++)
    #pragma unroll
    for (int j = 0; j < 2; j++) {
      int col = n0 + wn + j * 16 + mrow;
      #pragma unroll
      for (int r = 0; r < 4; r++) {
        int row = m0 + wm + i * 16 + rbase + r;
        C[(size_t)row * ldc + col] = acc[i][j][r];
      }
    }
}

// async global->LDS, 16 B per lane; lds base must be wave-uniform (lane i lands at base+16*i)
__device__ __forceinline__ void load_lds16(void* lds, const void* g) {
  __builtin_amdgcn_global_load_lds(
      (const __attribute__((address_space(1))) void*)g,
      (__attribute__((address_space(3))) void*)lds, 16, 0, 0);
}

// ---------- split-bf16 e-GEMM v2: m97-style 128x64 tile, BK=64, split-K=2 ----------
// grid (64,4,2) = 512 blocks (2/CU). z-half accumulates K in [z*512, z*512+512) into
// Cparts + z*M*ldc. 48 KB LDS (4 operand tiles via global_load_lds). 48 MFMA : 24 frag-reads.
__global__ __launch_bounds__(256) void k_gemm_e2(const short* __restrict__ Ah,
                                                 const short* __restrict__ Al,
                                                 const short* __restrict__ BTh,
                                                 const short* __restrict__ BTl,
                                                 float* __restrict__ Cparts,
                                                 int K, int ldc) {
  __shared__ __align__(16) short Ash[128][64];  // 16 KB
  __shared__ __align__(16) short Asl[128][64];  // 16 KB
  __shared__ __align__(16) short Bsh[64][64];   //  8 KB
  __shared__ __align__(16) short Bsl[64][64];   //  8 KB
  int m0 = blockIdx.x * 128, n0 = blockIdx.y * 64;
  int kz0 = blockIdx.z * 512;
  int tid = threadIdx.x, lane = tid & 63, wave = tid >> 6;
  int wm = wave * 32;
  int mrow = lane & 15, quad = lane >> 4;
  int lrow = lane >> 3, lseg = (lane & 7) * 8;

  f32x4 acc[2][4];
  #pragma unroll
  for (int i = 0; i < 2; i++)
    #pragma unroll
    for (int j = 0; j < 4; j++) acc[i][j] = (f32x4){0.f, 0.f, 0.f, 0.f};

  for (int k0 = kz0; k0 < kz0 + 512; k0 += 64) {
    __syncthreads();
    #pragma unroll
    for (int i = 0; i < 4; i++) {          // A hi/lo: 16 chunks each, 4 per wave
      int c = wave * 4 + i;
      size_t go = (size_t)(m0 + c * 8 + lrow) * K + k0 + lseg;
      load_lds16(&Ash[c * 8][0], Ah + go);
      load_lds16(&Asl[c * 8][0], Al + go);
    }
    #pragma unroll
    for (int i = 0; i < 2; i++) {          // B hi/lo: 8 chunks each, 2 per wave
      int c = wave * 2 + i;
      size_t go = (size_t)(n0 + c * 8 + lrow) * K + k0 + lseg;
      load_lds16(&Bsh[c * 8][0], BTh + go);
      load_lds16(&Bsl[c * 8][0], BTl + go);
    }
    __syncthreads();
    #pragma unroll
    for (int ks = 0; ks < 2; ks++) {
      int kk = ks * 32 + quad * 8;
      bf16x8 ah[2], al[2], bh[4], bl[4];
      #pragma unroll
      for (int i = 0; i < 2; i++) {
        ah[i] = *(const bf16x8*)&Ash[wm + i * 16 + mrow][kk];
        al[i] = *(const bf16x8*)&Asl[wm + i * 16 + mrow][kk];
      }
      #pragma unroll
      for (int j = 0; j < 4; j++) {
        bh[j] = *(const bf16x8*)&Bsh[j * 16 + mrow][kk];
        bl[j] = *(const bf16x8*)&Bsl[j * 16 + mrow][kk];
      }
      #pragma unroll
      for (int i = 0; i < 2; i++)
        #pragma unroll
        for (int j = 0; j < 4; j++) {
          acc[i][j] = __builtin_amdgcn_mfma_f32_16x16x32_bf16(ah[i], bh[j], acc[i][j], 0, 0, 0);
          acc[i][j] = __builtin_amdgcn_mfma_f32_16x16x32_bf16(ah[i], bl[j], acc[i][j], 0, 0, 0);
          acc[i][j] = __builtin_amdgcn_mfma_f32_16x16x32_bf16(al[i], bh[j], acc[i][j], 0, 0, 0);
        }
    }
  }
  float* C = Cparts + (size_t)blockIdx.z * 8192 * 256;
  int rbase = quad * 4;
  #pragma unroll
  for (int i = 0; i < 2; i++)
    #pragma unroll
    for (int j = 0; j < 4; j++) {
      int col = n0 + j * 16 + mrow;
      #pragma unroll
      for (int r = 0; r < 4; r++) {
        int row = m0 + wm + i * 16 + rbase + r;
        C[(size_t)row * ldc + col] = acc[i][j][r];
      }
    }
}

// ---------- final GEMM, m97-style: 128x64 tile, BK=64, global_load_lds(16B) ----------
__global__ __launch_bounds__(256) void k_gemm_f(const short* __restrict__ A,
                                                const short* __restrict__ BT,
                                                const float* __restrict__ bias,
                                                float* __restrict__ C,
                                                int K, int ldc, int nstore) {
  __shared__ __align__(16) short As[128][64];  // 16 KB, unpadded (async-copy layout)
  __shared__ __align__(16) short Bs[64][64];   //  8 KB
  int m0 = blockIdx.x * 128, n0 = blockIdx.y * 64;
  int tid = threadIdx.x, lane = tid & 63, wave = tid >> 6;
  int wm = wave * 32;
  int mrow = lane & 15, quad = lane >> 4;
  int lrow = lane >> 3, lseg = (lane & 7) * 8;

  f32x4 acc[2][4];
  #pragma unroll
  for (int i = 0; i < 2; i++)
    #pragma unroll
    for (int j = 0; j < 4; j++) acc[i][j] = (f32x4){0.f, 0.f, 0.f, 0.f};

  for (int k0 = 0; k0 < K; k0 += 64) {
    __syncthreads();
    #pragma unroll
    for (int i = 0; i < 4; i++) {
      int c = wave * 4 + i;
      load_lds16(&As[c * 8][0], A + (size_t)(m0 + c * 8 + lrow) * K + k0 + lseg);
    }
    #pragma unroll
    for (int i = 0; i < 2; i++) {
      int c = wave * 2 + i;
      load_lds16(&Bs[c * 8][0], BT + (size_t)(n0 + c * 8 + lrow) * K + k0 + lseg);
    }
    __syncthreads();
    #pragma unroll
    for (int ks = 0; ks < 2; ks++) {
      int kk = ks * 32 + quad * 8;
      bf16x8 af[2], bf[4];
      #pragma unroll
      for (int i = 0; i < 2; i++) af[i] = *(const bf16x8*)&As[wm + i * 16 + mrow][kk];
      #pragma unroll
      for (int j = 0; j < 4; j++) bf[j] = *(const bf16x8*)&Bs[j * 16 + mrow][kk];
      #pragma unroll
      for (int i = 0; i < 2; i++)
        #pragma unroll
        for (int j = 0; j < 4; j++)
          acc[i][j] = __builtin_amdgcn_mfma_f32_16x16x32_bf16(af[i], bf[j], acc[i][j], 0, 0, 0);
    }
  }
  int rbase = quad * 4;
  #pragma unroll
  for (int i = 0; i < 2; i++)
    #pragma unroll
    for (int j = 0; j < 4; j++) {
      int col = n0 + j * 16 + mrow;
      if (col < nstore) {
        float bv = bias[col];
        #pragma unroll
        for (int r = 0; r < 4; r++) {
          int row = m0 + wm + i * 16 + rbase + r;
          C[(size_t)row * ldc + col] = acc[i][j][r] + bv;
        }
      }
    }
}

// ---------- fused middle v9: v8 structure + sums the two split-K e-partials at load ----------
__global__ __launch_bounds__(512) void k_middle(const float* __restrict__ e0p,
                                                const float* __restrict__ e1p,
                                                const float* __restrict__ fb,
                                                const float* __restrict__ w3,
                                                const float* __restrict__ bias,
                                                short* __restrict__ cont) {
  __shared__ __align__(16) float fbs[40 * 256];  // 40 KB: (f+bias)*TANH_SCALE
  __shared__ float lg[16][40];
  __shared__ float attn[16][40];
  int tid = threadIdx.x, wave = tid >> 6, lane = tid & 63;
  int la = lane & 31, half = lane >> 5;
  int row0 = blockIdx.x * 16;
  int b = row0 >> 9;          // 512 rows per batch; 16 | 512 so block is batch-pure
  int lgrow = wave + (half ? 8 : 0);
  int myrow = row0 + lgrow;

  const float4* fsrc = (const float4*)(fb + (size_t)b * 40 * 256);
  const float4* bias4 = (const float4*)bias;
  for (int i = tid; i < 40 * 64; i += 512) {
    float4 v = fsrc[i];
    float4 bb = bias4[i & 63];
    v.x = (v.x + bb.x) * TANH_SCALE; v.y = (v.y + bb.y) * TANH_SCALE;
    v.z = (v.z + bb.z) * TANH_SCALE; v.w = (v.w + bb.w) * TANH_SCALE;
    ((float4*)fbs)[i] = v;
  }
  __syncthreads();

  int a0 = la * 8;
  size_t eoff = (size_t)myrow * 256 + a0;
  float4 p00 = *(const float4*)(e0p + eoff);
  float4 p01 = *(const float4*)(e0p + eoff + 4);
  float4 p10 = *(const float4*)(e1p + eoff);
  float4 p11 = *(const float4*)(e1p + eoff + 4);
  float4 e0, e1;
  e0.x = p00.x + p10.x; e0.y = p00.y + p10.y; e0.z = p00.z + p10.z; e0.w = p00.w + p10.w;
  e1.x = p01.x + p11.x; e1.y = p01.y + p11.y; e1.z = p01.z + p11.z; e1.w = p01.w + p11.w;
  float4 w30 = *(const float4*)(w3 + a0);
  float4 w31 = *(const float4*)(w3 + a0 + 4);
  float4 bv0 = *(const float4*)(bias + a0);
  float4 bv1 = *(const float4*)(bias + a0 + 4);
  float4 es0, es1;
  es0.x = e0.x * TANH_SCALE; es0.y = e0.y * TANH_SCALE;
  es0.z = e0.z * TANH_SCALE; es0.w = e0.w * TANH_SCALE;
  es1.x = e1.x * TANH_SCALE; es1.y = e1.y * TANH_SCALE;
  es1.z = e1.z * TANH_SCALE; es1.w = e1.w * TANH_SCALE;

  // phase 1: logits; chunks of 4 t -> 4 independent 5-step butterfly chains
  for (int tc = 0; tc < 40; tc += 4) {
    float p[4];
    #pragma unroll
    for (int u = 0; u < 4; u++) {
      const float* fr = &fbs[(tc + u) * 256 + a0];
      float4 f0 = *(const float4*)fr;
      float4 f1 = *(const float4*)(fr + 4);
      p[u] = tanh_pre(es0.x + f0.x) * w30.x + tanh_pre(es0.y + f0.y) * w30.y
           + tanh_pre(es0.z + f0.z) * w30.z + tanh_pre(es0.w + f0.w) * w30.w
           + tanh_pre(es1.x + f1.x) * w31.x + tanh_pre(es1.y + f1.y) * w31.y
           + tanh_pre(es1.z + f1.z) * w31.z + tanh_pre(es1.w + f1.w) * w31.w;
    }
    #pragma unroll
    for (int s = 16; s >= 1; s >>= 1) {
      #pragma unroll
      for (int u = 0; u < 4; u++) p[u] += __shfl_xor(p[u], s, 64);
    }
    if (la == 0) {
      #pragma unroll
      for (int u = 0; u < 4; u++) lg[lgrow][tc + u] = p[u];
    }
  }

  // phase 2: wave-local softmax per row
  auto softmax_row = [&](int r) {
    float x = (lane < 40) ? lg[r][lane] : -3.0e38f;
    float m = x;
    #pragma unroll
    for (int s = 32; s >= 1; s >>= 1) m = fmaxf(m, __shfl_xor(m, s, 64));
    float ex = (lane < 40) ? __builtin_amdgcn_exp2f((x - m) * 1.4426950408889634f) : 0.f;
    float ssum = ex;
    #pragma unroll
    for (int s = 32; s >= 1; s >>= 1) ssum += __shfl_xor(ssum, s, 64);
    if (lane < 40) attn[r][lane] = ex * __builtin_amdgcn_rcpf(ssum);
  };
  softmax_row(wave);
  softmax_row(wave + 8);

  // phase 3: text_attn (8-wide per lane) = (sum_t attn[t]*fbs_scaled[t]) * UNSCALE - bias
  float ac[8] = {0.f,0.f,0.f,0.f,0.f,0.f,0.f,0.f};
  for (int t = 0; t < 40; t++) {
    float w = attn[lgrow][t];
    const float* fr = &fbs[t * 256 + a0];
    float4 f0 = *(const float4*)fr;
    float4 f1 = *(const float4*)(fr + 4);
    ac[0] += w * f0.x; ac[1] += w * f0.y; ac[2] += w * f0.z; ac[3] += w * f0.w;
    ac[4] += w * f1.x; ac[5] += w * f1.y; ac[6] += w * f1.z; ac[7] += w * f1.w;
  }
  float tx[8];
  tx[0] = ac[0] * TANH_UNSCALE - bv0.x; tx[1] = ac[1] * TANH_UNSCALE - bv0.y;
  tx[2] = ac[2] * TANH_UNSCALE - bv0.z; tx[3] = ac[3] * TANH_UNSCALE - bv0.w;
  tx[4] = ac[4] * TANH_UNSCALE - bv1.x; tx[5] = ac[5] * TANH_UNSCALE - bv1.y;
  tx[6] = ac[6] * TANH_UNSCALE - bv1.z; tx[7] = ac[7] * TANH_UNSCALE - bv1.w;
  float ev[8] = {e0.x, e0.y, e0.z, e0.w, e1.x, e1.y, e1.z, e1.w};

  short* crow = cont + (size_t)myrow * 1024 + a0;
  auto st8 = [&](int off, const float* v) {
    bf16x8 pk;
    #pragma unroll
    for (int i = 0; i < 8; i++) pk[i] = cvt_bf16(v[i]);
    *(bf16x8*)(crow + off) = pk;
  };
  float s0[8], s1[8], s2[8], s3[8];
  #pragma unroll
  for (int i = 0; i < 8; i++) {
    s0[i] = tanh_fast(ev[i]);
    s1[i] = tanh_fast(tx[i]);
    s2[i] = tanh_fast(ev[i] * tx[i]);
    s3[i] = tanh_fast(ev[i] - tx[i]);
  }
  st8(0, s0); st8(256, s1); st8(512, s2); st8(768, s3);
}

extern "C" void kernel_launch(void* const* d_in, const int* in_sizes, int n_in,
                              void* d_out, int out_size, void* d_ws, size_t ws_size,
                              hipStream_t stream) {
  const float* video = (const float*)d_in[0];  // 16x512x1024
  const float* text  = (const float*)d_in[1];  // 16x40x300
  const float* w1    = (const float*)d_in[2];  // 1024x256
  const float* w2    = (const float*)d_in[3];  // 300x256
  const float* w3    = (const float*)d_in[4];  // 256
  const float* bias  = (const float*)d_in[5];  // 256
  const float* w4    = (const float*)d_in[6];  // 1024x500
  const float* b4    = (const float*)d_in[7];  // 500
  float* out = (float*)d_out;                  // 16x512x500
  char* ws = (char*)d_ws;

  // workspace layout (bytes)
  short* video_hi = (short*)(ws);              // 8192x1024 bf16 = 16,777,216
  short* video_lo = (short*)(ws + 16777216);   // 8192x1024 bf16 (aliased w/ contbuf)
  short* contbuf  = (short*)(ws + 16777216);   // dead until after e-GEMM consumes video_lo
  short* w1T_hi   = (short*)(ws + 33554432);   // 256x1024 bf16 = 524,288
  short* w1T_lo   = (short*)(ws + 34078720);   // 256x1024 bf16 = 524,288
  short* w4T      = (short*)(ws + 34603008);   // 512x1024 bf16 = 1,048,576
  float* fbuf     = (float*)(ws + 35651584);   // 16x40x256 f32 = 655,360 (f only)
  float* eparts   = (float*)(ws + 36306944);   // 2 x 8192x256 f32 = 16,777,216
  float* epart1   = (float*)(ws + 36306944 + 8388608);
  // text/w2 split staging aliases eparts (dead before e-GEMM runs; stream-ordered)
  short* text_hi  = (short*)(ws + 36306944);             // 640x320 bf16 = 409,600
  short* text_lo  = (short*)(ws + 36306944 + 409600);    // 640x320 bf16 = 409,600
  short* w2T_hi   = (short*)(ws + 36306944 + 819200);    // 256x320 bf16 = 204,800
  short* w2T_lo   = (short*)(ws + 36306944 + 1024000);   // 256x320 bf16 = 204,800

  k_prep<<<2032, 256, 0, stream>>>(video, text, w1, w2, w4,
                                   video_hi, video_lo, w1T_hi, w1T_lo, w4T,
                                   text_hi, text_lo, w2T_hi, w2T_lo);
  // fb = text @ w2  (M=640, N=256, K=320), ~f32 precision
  k_gemm_split<<<dim3(10, 4), 256, 0, stream>>>(text_hi, text_lo, w2T_hi, w2T_lo,
                                                fbuf, 320, 256);
  // e = video @ w1 (M=8192, N=256, K=1024), split-K=2 partials (overwrites text/w2 staging)
  k_gemm_e2<<<dim3(64, 4, 2), 256, 0, stream>>>(video_hi, video_lo, w1T_hi, w1T_lo,
                                                eparts, 1024, 256);
  k_middle<<<512, 512, 0, stream>>>(eparts, epart1, fbuf, w3, bias, contbuf);
  k_gemm_f<<<dim3(64, 8), 256, 0, stream>>>(contbuf, w4T, b4, out, 1024, 500, 500);
}